// Round 3
// baseline (200.201 us; speedup 1.0000x reference)
//
#include <hip/hip_runtime.h>
#include <math.h>
#include <stdint.h>

#define NB 16384
#define NG 10000
#define NGT 313           // ceil(NG/32) g-tiles of 32; tail rows NaN-poisoned
#define NCH 16            // g-chunks; chunk c covers tiles [NGT*c/NCH, NGT*(c+1)/NCH)
#define MAXTPC 20         // max tiles per chunk -> 20480 B LDS -> 8 blocks/CU = 32 waves/CU

typedef _Float16 half8 __attribute__((ext_vector_type(8)));
typedef float    floatx16 __attribute__((ext_vector_type(16)));

// C/D row map for 32x32x16: row = (r&3) + 8*(r>>2) + 4*kh  (g_local here)
#define ROWMAP(r, kh) (((r) & 3) + 8 * ((r) >> 2) + 4 * (kh))

// ---- stage chunk tiles [t0, t0+nt) into LDS, computing SH rows directly from gv ----
// row g >= NG -> all-NaN (loses every ordered compare and v_max -> never wins argmax)
__device__ inline void stage_sh(const float* __restrict__ gv, half8* lds, int t0, int nt) {
    const int nrows = nt * 32;
    for (int lr = threadIdx.x; lr < nrows; lr += 256) {
        int g = t0 * 32 + lr;
        half8 h0, h1;
        if (g >= NG) {
            const _Float16 qn = (_Float16)__builtin_nanf("");
#pragma unroll
            for (int i = 0; i < 8; ++i) { h0[i] = qn; h1[i] = qn; }
        } else {
            float x = gv[3 * g + 0], y = gv[3 * g + 1], z = gv[3 * g + 2];
            float n = sqrtf(x * x + y * y + z * z);
            float dn = fmaxf(n, 1e-12f);
            float vx = x / dn, vy = y / dn, vz = z / dn;
            float x2 = vx * vx, y2 = vy * vy, z2 = vz * vz;
            const float c_m4 = (float)(0.75 * sqrt(35.0 / M_PI));
            const float c_m3 = (float)(0.75 * sqrt(35.0 / (2.0 * M_PI)));
            const float c_m2 = (float)(0.75 * sqrt(5.0 / M_PI));
            const float c_m1 = (float)(0.75 * sqrt(5.0 / (2.0 * M_PI)));
            const float c_0  = (float)((3.0 / 16.0) * sqrt(1.0 / M_PI));
            const float c_p2 = (float)((3.0 / 8.0) * sqrt(5.0 / M_PI));
            const float c_p4 = (float)((3.0 / 16.0) * sqrt(35.0 / M_PI));
            h0[0] = (_Float16)(c_m4 * vx * vy * (x2 - y2));
            h0[1] = (_Float16)(c_m3 * vy * vz * (3.0f * x2 - y2));
            h0[2] = (_Float16)(c_m2 * vx * vy * (7.0f * z2 - 1.0f));
            h0[3] = (_Float16)(c_m1 * vy * vz * (7.0f * z2 - 3.0f));
            h0[4] = (_Float16)(c_0  * (35.0f * z2 * z2 - 30.0f * z2 + 3.0f));
            h0[5] = (_Float16)(c_m1 * vx * vz * (7.0f * z2 - 3.0f));
            h0[6] = (_Float16)(c_p2 * (x2 - y2) * (7.0f * z2 - 1.0f));
            h0[7] = (_Float16)(c_m3 * vx * vz * (x2 - y2));
            h1 = (half8){0, 0, 0, 0, 0, 0, 0, 0};
            h1[0] = (_Float16)(c_p4 * (x2 * x2 - 6.0f * x2 * y2 + y2 * y2));  // k=8
            h1[1] = (_Float16)x;   // k=9..11: raw grid vec
            h1[2] = (_Float16)y;
            h1[3] = (_Float16)z;
        }
        lds[lr * 2 + 0] = h0;
        lds[lr * 2 + 1] = h1;
    }
}

// B-operand frag (f4 for one b column): B[k][col]: col=lane&31, k=(lane>>5)*8+j.
__device__ inline half8 make_bfrag(const float* __restrict__ f4, int b, int kh) {
    half8 a = {0, 0, 0, 0, 0, 0, 0, 0};
    const float* fr = f4 + (size_t)b * 9;
    if (kh == 0) {
#pragma unroll
        for (int j = 0; j < 8; ++j) a[j] = (_Float16)fr[j];
    } else {
        a[0] = (_Float16)fr[8];      // k=8
    }
    return a;
}

// merge (v2,g2) into (v,g) with numpy first-max semantics
__device__ inline void merge_vg(float& v, int& g, float v2, int g2) {
    bool take = (v2 > v) || (v2 == v && g2 < g);
    v = take ? v2 : v;
    g = take ? g2 : g;
}

// ---------------- Kernel 1: pass-1 argmax, SH staged in-kernel, asm select ----------------
__global__ __launch_bounds__(256, 8) void k_pass1(const float* __restrict__ f4,
                                                  const float* __restrict__ gv,
                                                  float* __restrict__ Pv,
                                                  int* __restrict__ Pi) {
    __shared__ half8 lds[MAXTPC * 64];      // 20480 B -> 8 blocks/CU
    const int lane = threadIdx.x & 63;
    const int w = threadIdx.x >> 6;
    const int W = blockIdx.x * 4 + w;       // b-tile; b = 32W .. 32W+31
    const int n = lane & 31, kh = lane >> 5;
    const int chunk = blockIdx.y;
    const int b = W * 32 + n;

    const int t0 = (NGT * chunk) / NCH;
    const int t1 = (NGT * (chunk + 1)) / NCH;
    const int nt = t1 - t0;

    stage_sh(gv, lds, t0, nt);
    const half8 bf = make_bfrag(f4, b, kh);
    __syncthreads();

    float bv[16]; int bt[16];
#pragma unroll
    for (int r = 0; r < 16; ++r) { bv[r] = -INFINITY; bt[r] = 0; }

    const floatx16 zero16 = {0.f,0.f,0.f,0.f, 0.f,0.f,0.f,0.f, 0.f,0.f,0.f,0.f, 0.f,0.f,0.f,0.f};
    const half8* lp = &lds[n * 2 + kh];

    half8 af = *lp; lp += 64;
#pragma unroll 2
    for (int t = 0; t < nt - 1; ++t) {
        half8 afn = *lp; lp += 64;
        floatx16 c = __builtin_amdgcn_mfma_f32_32x32x16_f16(af, bf, zero16, 0, 0, 0);
        int tv = t;
#pragma unroll
        for (int r = 0; r < 16; ++r) {
            float cr = c[r];
            unsigned long long cc;   // private SGPR-pair cond reg -> chains independent
            asm("v_cmp_gt_f32 %2, %3, %0\n\t"
                "v_cndmask_b32 %1, %1, %4, %2\n\t"
                "v_max_f32 %0, %0, %3"
                : "+v"(bv[r]), "+v"(bt[r]), "=&s"(cc)
                : "v"(cr), "v"(tv));
        }
        af = afn;
    }
    {
        floatx16 c = __builtin_amdgcn_mfma_f32_32x32x16_f16(af, bf, zero16, 0, 0, 0);
        int tv = nt - 1;
#pragma unroll
        for (int r = 0; r < 16; ++r) {
            float cr = c[r];
            unsigned long long cc;
            asm("v_cmp_gt_f32 %2, %3, %0\n\t"
                "v_cndmask_b32 %1, %1, %4, %2\n\t"
                "v_max_f32 %0, %0, %3"
                : "+v"(bv[r]), "+v"(bt[r]), "=&s"(cc)
                : "v"(cr), "v"(tv));
        }
    }
    float v = bv[0]; int g = ((t0 + bt[0]) << 5) + ROWMAP(0, kh);
#pragma unroll
    for (int r = 1; r < 16; ++r)
        merge_vg(v, g, bv[r], ((t0 + bt[r]) << 5) + ROWMAP(r, kh));
    merge_vg(v, g, __shfl_xor(v, 32), __shfl_xor(g, 32));
    if (kh == 0) {
        Pv[(size_t)chunk * NB + b] = v;
        Pi[(size_t)chunk * NB + b] = g;
    }
}

// ---------------- Kernel 2: pass-2 masked argmax, dual MFMA, SH staged in-kernel ----------------
__global__ __launch_bounds__(256, 8) void k_pass2(const float* __restrict__ f4,
                                                  const float* __restrict__ gv,
                                                  const float* __restrict__ P1v,
                                                  const int* __restrict__ P1i,
                                                  float* __restrict__ P2v,
                                                  int* __restrict__ P2i) {
    __shared__ half8 lds[MAXTPC * 64];
    const int lane = threadIdx.x & 63;
    const int w = threadIdx.x >> 6;
    const int W = blockIdx.x * 4 + w;
    const int n = lane & 31, kh = lane >> 5;
    const int chunk = blockIdx.y;
    const int b = W * 32 + n;

    const int t0 = (NGT * chunk) / NCH;
    const int t1 = (NGT * (chunk + 1)) / NCH;
    const int nt = t1 - t0;

    stage_sh(gv, lds, t0, nt);

    const half8 bf = make_bfrag(f4, b, kh);

    float bvv = -INFINITY; int zi = 0;
#pragma unroll
    for (int cc = 0; cc < NCH; ++cc) {
        float vv = P1v[(size_t)cc * NB + b];
        int   ii = P1i[(size_t)cc * NB + b];
        merge_vg(bvv, zi, vv, ii);
    }
    half8 df = {0, 0, 0, 0, 0, 0, 0, 0};
    if (kh == 1) {                           // z_b at k=9,10,11 -> j=1..3
        df[1] = (_Float16)gv[3 * zi + 0];
        df[2] = (_Float16)gv[3 * zi + 1];
        df[3] = (_Float16)gv[3 * zi + 2];
    }
    __syncthreads();

    float bv[16]; int bt[16];
#pragma unroll
    for (int r = 0; r < 16; ++r) { bv[r] = -INFINITY; bt[r] = 0; }

    const floatx16 zero16 = {0.f,0.f,0.f,0.f, 0.f,0.f,0.f,0.f, 0.f,0.f,0.f,0.f, 0.f,0.f,0.f,0.f};
    const float ninf = -INFINITY;
    const float lim = 0.2f;
    const half8* lp = &lds[n * 2 + kh];

    half8 af = *lp; lp += 64;
#pragma unroll 2
    for (int t = 0; t < nt - 1; ++t) {
        half8 afn = *lp; lp += 64;
        floatx16 cs = __builtin_amdgcn_mfma_f32_32x32x16_f16(af, bf, zero16, 0, 0, 0);
        floatx16 cd = __builtin_amdgcn_mfma_f32_32x32x16_f16(af, df, zero16, 0, 0, 0);
        int tv = t;
#pragma unroll
        for (int r = 0; r < 16; ++r) {
            float cr = cs[r], dr = cd[r], sm;
            unsigned long long cc;
            // %2=cond ; sm = (0.2>|cd|) ? cs : -inf ; bt = (sm>bv) ? t : bt ; bv = max(bv,sm)
            asm("v_cmp_gt_f32 %2, %8, |%4|\n\t"
                "v_cndmask_b32 %5, %6, %3, %2\n\t"
                "v_cmp_gt_f32 %2, %5, %0\n\t"
                "v_cndmask_b32 %1, %1, %7, %2\n\t"
                "v_max_f32 %0, %0, %5"
                : "+v"(bv[r]), "+v"(bt[r]), "=&s"(cc), "+v"(cr), "+v"(dr), "=&v"(sm)
                : "v"(ninf), "v"(tv), "s"(lim));
        }
        af = afn;
    }
    {
        floatx16 cs = __builtin_amdgcn_mfma_f32_32x32x16_f16(af, bf, zero16, 0, 0, 0);
        floatx16 cd = __builtin_amdgcn_mfma_f32_32x32x16_f16(af, df, zero16, 0, 0, 0);
        int tv = nt - 1;
#pragma unroll
        for (int r = 0; r < 16; ++r) {
            float cr = cs[r], dr = cd[r], sm;
            unsigned long long cc;
            asm("v_cmp_gt_f32 %2, %8, |%4|\n\t"
                "v_cndmask_b32 %5, %6, %3, %2\n\t"
                "v_cmp_gt_f32 %2, %5, %0\n\t"
                "v_cndmask_b32 %1, %1, %7, %2\n\t"
                "v_max_f32 %0, %0, %5"
                : "+v"(bv[r]), "+v"(bt[r]), "=&s"(cc), "+v"(cr), "+v"(dr), "=&v"(sm)
                : "v"(ninf), "v"(tv), "s"(lim));
        }
    }
    float v = bv[0]; int g = ((t0 + bt[0]) << 5) + ROWMAP(0, kh);
#pragma unroll
    for (int r = 1; r < 16; ++r)
        merge_vg(v, g, bv[r], ((t0 + bt[r]) << 5) + ROWMAP(r, kh));
    merge_vg(v, g, __shfl_xor(v, 32), __shfl_xor(g, 32));
    if (kh == 0) {
        P2v[(size_t)chunk * NB + b] = v;
        P2i[(size_t)chunk * NB + b] = g;
    }
}

// ---------------- Kernel 3: finalize — combine both passes, frame, quaternion, boundary map ----------------
__global__ __launch_bounds__(256) void k_final(const float* __restrict__ f0,
                                               const float* __restrict__ gv,
                                               const float* __restrict__ P1v,
                                               const int* __restrict__ P1i,
                                               const float* __restrict__ P2v,
                                               const int* __restrict__ P2i,
                                               float* __restrict__ out) {
    int b = blockIdx.x * 256 + threadIdx.x;
    float bz = -INFINITY; int zi = 0;
#pragma unroll
    for (int cc = 0; cc < NCH; ++cc) {
        float v = P1v[(size_t)cc * NB + b];
        int   i = P1i[(size_t)cc * NB + b];
        if (v > bz || (v == bz && i < zi)) { bz = v; zi = i; }
    }
    float bx = -INFINITY; int xi = 0;
#pragma unroll
    for (int cc = 0; cc < NCH; ++cc) {
        float v = P2v[(size_t)cc * NB + b];
        int   i = P2i[(size_t)cc * NB + b];
        if (v > bx || (v == bx && i < xi)) { bx = v; xi = i; }
    }
    float zr0 = gv[3 * zi], zr1 = gv[3 * zi + 1], zr2 = gv[3 * zi + 2];
    float xr0 = gv[3 * xi], xr1 = gv[3 * xi + 1], xr2 = gv[3 * xi + 2];
    float zn = sqrtf(zr0 * zr0 + zr1 * zr1 + zr2 * zr2);
    float zd = fmaxf(zn, 1e-12f);
    float z0 = zr0 / zd, z1 = zr1 / zd, z2 = zr2 / zd;
    float pr = xr0 * z0 + xr1 * z1 + xr2 * z2;
    float ux = xr0 - pr * z0, uy = xr1 - pr * z1, uz = xr2 - pr * z2;
    float xn = sqrtf(ux * ux + uy * uy + uz * uz);
    float xd = fmaxf(xn, 1e-12f);
    float x0 = ux / xd, x1 = uy / xd, x2 = uz / xd;
    float y0 = z1 * x2 - z2 * x1;
    float y1 = z2 * x0 - z0 * x2;
    float y2 = z0 * x1 - z1 * x0;
    float m00 = x0, m01 = y0, m02 = z0;
    float m10 = x1, m11 = y1, m12 = z1;
    float m20 = x2, m21 = y2, m22 = z2;
    float q0 = sqrtf(fmaxf(1.0f + m00 + m11 + m22, 0.0f));
    float q1 = sqrtf(fmaxf(1.0f + m00 - m11 - m22, 0.0f));
    float q2 = sqrtf(fmaxf(1.0f - m00 + m11 - m22, 0.0f));
    float q3 = sqrtf(fmaxf(1.0f - m00 - m11 + m22, 0.0f));
    int bq = 0; float qb = q0;
    if (q1 > qb) { qb = q1; bq = 1; }
    if (q2 > qb) { qb = q2; bq = 2; }
    if (q3 > qb) { qb = q3; bq = 3; }
    float dd = 2.0f * fmaxf(qb, 0.1f);
    float wq, qx, qy, qz;
    if (bq == 0)      { wq = q0 * q0;  qx = m21 - m12; qy = m02 - m20; qz = m10 - m01; }
    else if (bq == 1) { wq = m21 - m12; qx = q1 * q1;  qy = m10 + m01; qz = m02 + m20; }
    else if (bq == 2) { wq = m02 - m20; qx = m10 + m01; qy = q2 * q2;  qz = m12 + m21; }
    else              { wq = m10 - m01; qx = m20 + m02; qy = m21 + m12; qz = q3 * q3; }
    out[b * 4 + 0] = wq / dd;
    out[b * 4 + 1] = qx / dd;
    out[b * 4 + 2] = qy / dd;
    out[b * 4 + 3] = qz / dd;
    out[4 * NB + b] = f0[b] * (float)(180.0 / M_PI);
}

extern "C" void kernel_launch(void* const* d_in, const int* in_sizes, int n_in,
                              void* d_out, int out_size, void* d_ws, size_t ws_size,
                              hipStream_t stream) {
    const float* f0 = (const float*)d_in[0];   // [16384, 1]
    const float* f4 = (const float*)d_in[2];   // [16384, 9]
    const float* gv = (const float*)d_in[4];   // [10000, 3]
    float* out = (float*)d_out;
    (void)in_sizes; (void)n_in; (void)out_size; (void)ws_size;

    // ws layout (bytes): P1v 1M | P1i 1M | P2v 1M | P2i 1M  (4 MB; ws is ~268 MB)
    char* W = (char*)d_ws;
    float* P1v = (float*)(W + 0);
    int*   P1i = (int*)(W + 1048576);
    float* P2v = (float*)(W + 2 * 1048576);
    int*   P2i = (int*)(W + 3 * 1048576);

    // 512 b-tiles / 4 waves = 128 blocks x; 16 chunks y = 2048 blocks -> 8/CU (20480 B LDS)
    dim3 grid2(128, NCH);
    k_pass1<<<grid2, 256, 0, stream>>>(f4, gv, P1v, P1i);
    k_pass2<<<grid2, 256, 0, stream>>>(f4, gv, P1v, P1i, P2v, P2i);
    k_final<<<NB / 256, 256, 0, stream>>>(f0, gv, P1v, P1i, P2v, P2i, out);
}

// Round 4
// 141.361 us; speedup vs baseline: 1.4162x; 1.4162x over previous
//
#include <hip/hip_runtime.h>
#include <math.h>
#include <stdint.h>

#define NB 16384
#define NG 10000
#define NGT 625           // NG / 16 exactly -> no tail poisoning needed
#define NCH 20            // g-chunks; chunk c covers tiles [NGT*c/NCH, NGT*(c+1)/NCH)
#define MAXTPC 32         // max tiles/chunk: 32 tiles * 16 rows * 20 halfs * 2B = 20480 B LDS
#define ROWP 20           // halfs per LDS row: 16 data + 4 pad (40 B pitch -> no bank conflict)

typedef _Float16 half4 __attribute__((ext_vector_type(4)));
typedef float    floatx4 __attribute__((ext_vector_type(4)));

// mfma_f32_16x16x16f16 layouts (shape-determined, m89/m101):
//   A: row = lane&15, k = (lane>>4)*4 + j   (2 VGPRs / half4)
//   B: col = lane&15, k = (lane>>4)*4 + j
//   C/D: col = lane&15, row = (lane>>4)*4 + r
// K=16 holds: k0..8 = SH0..8, k9..11 = raw grid vec (pass2 dot), k12..15 = 0.

// ---- stage chunk tiles [t0, t0+nt) into LDS: 16-row g-tiles, 40B row pitch ----
__device__ inline void stage_sh(const float* __restrict__ gv, _Float16* lds, int t0, int nt) {
    const int nrows = nt * 16;            // <= 512; 10000 = 16*625 exact, no tail
    for (int lr = threadIdx.x; lr < nrows; lr += 256) {
        int g = t0 * 16 + lr;
        float x = gv[3 * g + 0], y = gv[3 * g + 1], z = gv[3 * g + 2];
        float n = sqrtf(x * x + y * y + z * z);
        float dn = fmaxf(n, 1e-12f);
        float vx = x / dn, vy = y / dn, vz = z / dn;
        float x2 = vx * vx, y2 = vy * vy, z2 = vz * vz;
        const float c_m4 = (float)(0.75 * sqrt(35.0 / M_PI));
        const float c_m3 = (float)(0.75 * sqrt(35.0 / (2.0 * M_PI)));
        const float c_m2 = (float)(0.75 * sqrt(5.0 / M_PI));
        const float c_m1 = (float)(0.75 * sqrt(5.0 / (2.0 * M_PI)));
        const float c_0  = (float)((3.0 / 16.0) * sqrt(1.0 / M_PI));
        const float c_p2 = (float)((3.0 / 8.0) * sqrt(5.0 / M_PI));
        const float c_p4 = (float)((3.0 / 16.0) * sqrt(35.0 / M_PI));
        half4 s0, s1, s2, s3;
        s0[0] = (_Float16)(c_m4 * vx * vy * (x2 - y2));
        s0[1] = (_Float16)(c_m3 * vy * vz * (3.0f * x2 - y2));
        s0[2] = (_Float16)(c_m2 * vx * vy * (7.0f * z2 - 1.0f));
        s0[3] = (_Float16)(c_m1 * vy * vz * (7.0f * z2 - 3.0f));
        s1[0] = (_Float16)(c_0  * (35.0f * z2 * z2 - 30.0f * z2 + 3.0f));
        s1[1] = (_Float16)(c_m1 * vx * vz * (7.0f * z2 - 3.0f));
        s1[2] = (_Float16)(c_p2 * (x2 - y2) * (7.0f * z2 - 1.0f));
        s1[3] = (_Float16)(c_m3 * vx * vz * (x2 - y2));
        s2[0] = (_Float16)(c_p4 * (x2 * x2 - 6.0f * x2 * y2 + y2 * y2));  // k=8
        s2[1] = (_Float16)x;   // k=9..11: raw grid vec
        s2[2] = (_Float16)y;
        s2[3] = (_Float16)z;
        s3 = (half4){0, 0, 0, 0};
        _Float16* row = lds + lr * ROWP;
        *(half4*)(row + 0)  = s0;
        *(half4*)(row + 4)  = s1;
        *(half4*)(row + 8)  = s2;
        *(half4*)(row + 12) = s3;
    }
}

// B-operand frag for column b, k-group kg: f4 comps at k=0..8, zeros above.
__device__ inline half4 make_bfrag(const float* __restrict__ f4, int b, int kg) {
    half4 a = {0, 0, 0, 0};
    const float* fr = f4 + (size_t)b * 9;
    if (kg == 0) {
        a[0] = (_Float16)fr[0]; a[1] = (_Float16)fr[1];
        a[2] = (_Float16)fr[2]; a[3] = (_Float16)fr[3];
    } else if (kg == 1) {
        a[0] = (_Float16)fr[4]; a[1] = (_Float16)fr[5];
        a[2] = (_Float16)fr[6]; a[3] = (_Float16)fr[7];
    } else if (kg == 2) {
        a[0] = (_Float16)fr[8];      // k=8
    }
    return a;
}

// merge (v2,g2) into (v,g) with numpy first-max semantics
__device__ inline void merge_vg(float& v, int& g, float v2, int g2) {
    bool take = (v2 > v) || (v2 == v && g2 < g);
    v = take ? v2 : v;
    g = take ? g2 : g;
}

// ---------------- Kernel 1: pass-1 argmax ----------------
__global__ __launch_bounds__(256, 8) void k_pass1(const float* __restrict__ f4,
                                                  const float* __restrict__ gv,
                                                  float* __restrict__ Pv,
                                                  int* __restrict__ Pi) {
    __shared__ _Float16 lds[MAXTPC * 16 * ROWP];   // 20480 B -> 8 blocks/CU
    const int lane = threadIdx.x & 63;
    const int w = threadIdx.x >> 6;
    const int W = blockIdx.x * 4 + w;       // b-tile of 16; b = 16W + col
    const int col = lane & 15, kg = lane >> 4;
    const int chunk = blockIdx.y;
    const int b = W * 16 + col;

    const int t0 = (NGT * chunk) / NCH;
    const int t1 = (NGT * (chunk + 1)) / NCH;
    const int nt = t1 - t0;

    stage_sh(gv, lds, t0, nt);
    const half4 bf = make_bfrag(f4, b, kg);
    __syncthreads();

    float bv[4]; int bt[4];
#pragma unroll
    for (int r = 0; r < 4; ++r) { bv[r] = -INFINITY; bt[r] = 0; }

    const floatx4 zero4 = {0.f, 0.f, 0.f, 0.f};
    const _Float16* lp = &lds[col * ROWP + kg * 4];

    half4 af = *(const half4*)lp; lp += 16 * ROWP;
#pragma unroll 2
    for (int t = 0; t < nt - 1; ++t) {
        half4 afn = *(const half4*)lp; lp += 16 * ROWP;
        floatx4 c = __builtin_amdgcn_mfma_f32_16x16x16f16(af, bf, zero4, 0, 0, 0);
        int tv = t;
#pragma unroll
        for (int r = 0; r < 4; ++r) {
            float cr = c[r];
            unsigned long long cc;   // private SGPR-pair cond reg -> chains independent
            asm("v_cmp_gt_f32 %2, %3, %0\n\t"
                "v_cndmask_b32 %1, %1, %4, %2\n\t"
                "v_max_f32 %0, %0, %3"
                : "+v"(bv[r]), "+v"(bt[r]), "=&s"(cc)
                : "v"(cr), "v"(tv));
        }
        af = afn;
    }
    {
        floatx4 c = __builtin_amdgcn_mfma_f32_16x16x16f16(af, bf, zero4, 0, 0, 0);
        int tv = nt - 1;
#pragma unroll
        for (int r = 0; r < 4; ++r) {
            float cr = c[r];
            unsigned long long cc;
            asm("v_cmp_gt_f32 %2, %3, %0\n\t"
                "v_cndmask_b32 %1, %1, %4, %2\n\t"
                "v_max_f32 %0, %0, %3"
                : "+v"(bv[r]), "+v"(bt[r]), "=&s"(cc)
                : "v"(cr), "v"(tv));
        }
    }
    // merge 4 regs (g ascending in r) then across the 4 k-groups
    float v = bv[0]; int g = ((t0 + bt[0]) << 4) + (kg << 2);
#pragma unroll
    for (int r = 1; r < 4; ++r)
        merge_vg(v, g, bv[r], ((t0 + bt[r]) << 4) + (kg << 2) + r);
    merge_vg(v, g, __shfl_xor(v, 16), __shfl_xor(g, 16));
    merge_vg(v, g, __shfl_xor(v, 32), __shfl_xor(g, 32));
    if (lane < 16) {
        Pv[(size_t)chunk * NB + b] = v;
        Pi[(size_t)chunk * NB + b] = g;
    }
}

// ---------------- Kernel 1.5: reduce P1 across chunks -> z-axis per b (coalesced) ----------------
__global__ __launch_bounds__(256) void k_zred(const float* __restrict__ P1v,
                                              const int* __restrict__ P1i,
                                              const float* __restrict__ gv,
                                              float* __restrict__ zax) {
    const int b = blockIdx.x * 256 + threadIdx.x;
    float bz = -INFINITY; int zi = 0;
#pragma unroll
    for (int cc = 0; cc < NCH; ++cc) {
        float v = P1v[(size_t)cc * NB + b];
        int   i = P1i[(size_t)cc * NB + b];
        if (v > bz || (v == bz && i < zi)) { bz = v; zi = i; }
    }
    floatx4 z4 = {gv[3 * zi + 0], gv[3 * zi + 1], gv[3 * zi + 2], 0.f};
    *(floatx4*)(zax + 4 * (size_t)b) = z4;
}

// ---------------- Kernel 2: pass-2 masked argmax, dual MFMA ----------------
__global__ __launch_bounds__(256, 8) void k_pass2(const float* __restrict__ f4,
                                                  const float* __restrict__ gv,
                                                  const float* __restrict__ zax,
                                                  float* __restrict__ P2v,
                                                  int* __restrict__ P2i) {
    __shared__ _Float16 lds[MAXTPC * 16 * ROWP];
    const int lane = threadIdx.x & 63;
    const int w = threadIdx.x >> 6;
    const int W = blockIdx.x * 4 + w;
    const int col = lane & 15, kg = lane >> 4;
    const int chunk = blockIdx.y;
    const int b = W * 16 + col;

    const int t0 = (NGT * chunk) / NCH;
    const int t1 = (NGT * (chunk + 1)) / NCH;
    const int nt = t1 - t0;

    stage_sh(gv, lds, t0, nt);
    const half4 bf = make_bfrag(f4, b, kg);
    half4 df = {0, 0, 0, 0};
    if (kg == 2) {                           // z_b at k=9,10,11 -> j=1..3
        const float* zp = zax + 4 * (size_t)b;
        df[1] = (_Float16)zp[0];
        df[2] = (_Float16)zp[1];
        df[3] = (_Float16)zp[2];
    }
    __syncthreads();

    float bv[4]; int bt[4];
#pragma unroll
    for (int r = 0; r < 4; ++r) { bv[r] = -INFINITY; bt[r] = 0; }

    const floatx4 zero4 = {0.f, 0.f, 0.f, 0.f};
    const float ninf = -INFINITY;
    const float lim = 0.2f;
    const _Float16* lp = &lds[col * ROWP + kg * 4];

    half4 af = *(const half4*)lp; lp += 16 * ROWP;
#pragma unroll 2
    for (int t = 0; t < nt - 1; ++t) {
        half4 afn = *(const half4*)lp; lp += 16 * ROWP;
        floatx4 cs = __builtin_amdgcn_mfma_f32_16x16x16f16(af, bf, zero4, 0, 0, 0);
        floatx4 cd = __builtin_amdgcn_mfma_f32_16x16x16f16(af, df, zero4, 0, 0, 0);
        int tv = t;
#pragma unroll
        for (int r = 0; r < 4; ++r) {
            float cr = cs[r], dr = cd[r], sm;
            unsigned long long cc;
            // sm = (0.2>|cd|) ? cs : -inf ; bt = (sm>bv) ? t : bt ; bv = max(bv,sm)
            asm("v_cmp_gt_f32 %2, %8, |%4|\n\t"
                "v_cndmask_b32 %5, %6, %3, %2\n\t"
                "v_cmp_gt_f32 %2, %5, %0\n\t"
                "v_cndmask_b32 %1, %1, %7, %2\n\t"
                "v_max_f32 %0, %0, %5"
                : "+v"(bv[r]), "+v"(bt[r]), "=&s"(cc), "+v"(cr), "+v"(dr), "=&v"(sm)
                : "v"(ninf), "v"(tv), "s"(lim));
        }
        af = afn;
    }
    {
        floatx4 cs = __builtin_amdgcn_mfma_f32_16x16x16f16(af, bf, zero4, 0, 0, 0);
        floatx4 cd = __builtin_amdgcn_mfma_f32_16x16x16f16(af, df, zero4, 0, 0, 0);
        int tv = nt - 1;
#pragma unroll
        for (int r = 0; r < 4; ++r) {
            float cr = cs[r], dr = cd[r], sm;
            unsigned long long cc;
            asm("v_cmp_gt_f32 %2, %8, |%4|\n\t"
                "v_cndmask_b32 %5, %6, %3, %2\n\t"
                "v_cmp_gt_f32 %2, %5, %0\n\t"
                "v_cndmask_b32 %1, %1, %7, %2\n\t"
                "v_max_f32 %0, %0, %5"
                : "+v"(bv[r]), "+v"(bt[r]), "=&s"(cc), "+v"(cr), "+v"(dr), "=&v"(sm)
                : "v"(ninf), "v"(tv), "s"(lim));
        }
    }
    float v = bv[0]; int g = ((t0 + bt[0]) << 4) + (kg << 2);
#pragma unroll
    for (int r = 1; r < 4; ++r)
        merge_vg(v, g, bv[r], ((t0 + bt[r]) << 4) + (kg << 2) + r);
    merge_vg(v, g, __shfl_xor(v, 16), __shfl_xor(g, 16));
    merge_vg(v, g, __shfl_xor(v, 32), __shfl_xor(g, 32));
    if (lane < 16) {
        P2v[(size_t)chunk * NB + b] = v;
        P2i[(size_t)chunk * NB + b] = g;
    }
}

// ---------------- Kernel 3: finalize — frame, quaternion, boundary map ----------------
__global__ __launch_bounds__(256) void k_final(const float* __restrict__ f0,
                                               const float* __restrict__ gv,
                                               const float* __restrict__ zax,
                                               const float* __restrict__ P2v,
                                               const int* __restrict__ P2i,
                                               float* __restrict__ out) {
    int b = blockIdx.x * 256 + threadIdx.x;
    float bx = -INFINITY; int xi = 0;
#pragma unroll
    for (int cc = 0; cc < NCH; ++cc) {
        float v = P2v[(size_t)cc * NB + b];
        int   i = P2i[(size_t)cc * NB + b];
        if (v > bx || (v == bx && i < xi)) { bx = v; xi = i; }
    }
    const float* zp = zax + 4 * (size_t)b;
    float zr0 = zp[0], zr1 = zp[1], zr2 = zp[2];
    float xr0 = gv[3 * xi], xr1 = gv[3 * xi + 1], xr2 = gv[3 * xi + 2];
    float zn = sqrtf(zr0 * zr0 + zr1 * zr1 + zr2 * zr2);
    float zd = fmaxf(zn, 1e-12f);
    float z0 = zr0 / zd, z1 = zr1 / zd, z2 = zr2 / zd;
    float pr = xr0 * z0 + xr1 * z1 + xr2 * z2;
    float ux = xr0 - pr * z0, uy = xr1 - pr * z1, uz = xr2 - pr * z2;
    float xn = sqrtf(ux * ux + uy * uy + uz * uz);
    float xd = fmaxf(xn, 1e-12f);
    float x0 = ux / xd, x1 = uy / xd, x2 = uz / xd;
    float y0 = z1 * x2 - z2 * x1;
    float y1 = z2 * x0 - z0 * x2;
    float y2 = z0 * x1 - z1 * x0;
    float m00 = x0, m01 = y0, m02 = z0;
    float m10 = x1, m11 = y1, m12 = z1;
    float m20 = x2, m21 = y2, m22 = z2;
    float q0 = sqrtf(fmaxf(1.0f + m00 + m11 + m22, 0.0f));
    float q1 = sqrtf(fmaxf(1.0f + m00 - m11 - m22, 0.0f));
    float q2 = sqrtf(fmaxf(1.0f - m00 + m11 - m22, 0.0f));
    float q3 = sqrtf(fmaxf(1.0f - m00 - m11 + m22, 0.0f));
    int bq = 0; float qb = q0;
    if (q1 > qb) { qb = q1; bq = 1; }
    if (q2 > qb) { qb = q2; bq = 2; }
    if (q3 > qb) { qb = q3; bq = 3; }
    float dd = 2.0f * fmaxf(qb, 0.1f);
    float wq, qx, qy, qz;
    if (bq == 0)      { wq = q0 * q0;  qx = m21 - m12; qy = m02 - m20; qz = m10 - m01; }
    else if (bq == 1) { wq = m21 - m12; qx = q1 * q1;  qy = m10 + m01; qz = m02 + m20; }
    else if (bq == 2) { wq = m02 - m20; qx = m10 + m01; qy = q2 * q2;  qz = m12 + m21; }
    else              { wq = m10 - m01; qx = m20 + m02; qy = m21 + m12; qz = q3 * q3; }
    out[b * 4 + 0] = wq / dd;
    out[b * 4 + 1] = qx / dd;
    out[b * 4 + 2] = qy / dd;
    out[b * 4 + 3] = qz / dd;
    out[4 * NB + b] = f0[b] * (float)(180.0 / M_PI);
}

extern "C" void kernel_launch(void* const* d_in, const int* in_sizes, int n_in,
                              void* d_out, int out_size, void* d_ws, size_t ws_size,
                              hipStream_t stream) {
    const float* f0 = (const float*)d_in[0];   // [16384, 1]
    const float* f4 = (const float*)d_in[2];   // [16384, 9]
    const float* gv = (const float*)d_in[4];   // [10000, 3]
    float* out = (float*)d_out;
    (void)in_sizes; (void)n_in; (void)out_size; (void)ws_size;

    // ws layout (1.5 MB stride): P1v | P1i | P2v | P2i | zax (each <= 1.31 MB)
    char* W = (char*)d_ws;
    float* P1v = (float*)(W + 0);
    int*   P1i = (int*)(W + 0x180000);
    float* P2v = (float*)(W + 2 * 0x180000);
    int*   P2i = (int*)(W + 3 * 0x180000);
    float* zax = (float*)(W + 4 * 0x180000);   // [NB][4] floats

    // 1024 b-tiles of 16 / 4 waves = 256 blocks x; 20 chunks y -> 5120 blocks, 8/CU resident
    dim3 grid2(256, NCH);
    k_pass1<<<grid2, 256, 0, stream>>>(f4, gv, P1v, P1i);
    k_zred<<<NB / 256, 256, 0, stream>>>(P1v, P1i, gv, zax);
    k_pass2<<<grid2, 256, 0, stream>>>(f4, gv, zax, P2v, P2i);
    k_final<<<NB / 256, 256, 0, stream>>>(f0, gv, zax, P2v, P2i, out);
}

// Round 6
// 116.207 us; speedup vs baseline: 1.7228x; 1.2165x over previous
//
#include <hip/hip_runtime.h>
#include <math.h>
#include <stdint.h>

#define NB 16384
#define NG 10000
#define NGT 313           // ceil(NG/32) g-tiles of 32; tail rows NaN -> scrubbed in peeled iter
#define NCH 20            // g-chunks; chunk c covers tiles [NGT*c/NCH, NGT*(c+1)/NCH)
#define MAXTPC 16         // max tiles/chunk: 16 * 32 rows * 40 B = 20480 B LDS -> 8 blocks/CU

typedef _Float16 half4 __attribute__((ext_vector_type(4)));
typedef _Float16 half8 __attribute__((ext_vector_type(8)));
typedef float    floatx16 __attribute__((ext_vector_type(16)));

// C/D row map for 32x32x16: row = (r&3) + 8*(r>>2) + 4*kh
#define ROWMAP(r, kh) (((r) & 3) + 8 * ((r) >> 2) + 4 * (kh))

__device__ inline float max3f(float a, float b, float c) {
    float d;
    asm("v_max3_f32 %0, %1, %2, %3" : "=v"(d) : "v"(a), "v"(b), "v"(c));
    return d;
}

// p = bitcast( (bits(c) & 0xFFFFFFF0) | F )  -- pack 4-bit field into low mantissa
#define PACKF(p_, c_, F_) \
    asm("v_and_or_b32 %0, %1, %2, " F_ : "=v"(p_) : "v"(c_), "s"(mskc))

// ---- stage chunk tiles [t0, t0+nt) into LDS (32-row tiles, 40 B row pitch) ----
// row g >= NG -> all-NaN halfs (MFMA output NaN; pass1 scrubs, pass2 mask kills)
__device__ inline void stage_sh(const float* __restrict__ gv, half4* lds4, int t0, int nt) {
    const int nrows = nt * 32;
    for (int lr = threadIdx.x; lr < nrows; lr += 256) {
        int g = t0 * 32 + lr;
        half4 s0, s1, s2, s3;
        if (g >= NG) {
            const _Float16 qn = (_Float16)__builtin_nanf("");
            s0 = (half4){qn, qn, qn, qn}; s1 = s0; s2 = s0; s3 = s0;
        } else {
            float x = gv[3 * g + 0], y = gv[3 * g + 1], z = gv[3 * g + 2];
            float n2 = x * x + y * y + z * z;
            float rn = __frsqrt_rn(fmaxf(n2, 1e-24f));
            float vx = x * rn, vy = y * rn, vz = z * rn;
            float x2 = vx * vx, y2 = vy * vy, z2 = vz * vz;
            const float c_m4 = (float)(0.75 * sqrt(35.0 / M_PI));
            const float c_m3 = (float)(0.75 * sqrt(35.0 / (2.0 * M_PI)));
            const float c_m2 = (float)(0.75 * sqrt(5.0 / M_PI));
            const float c_m1 = (float)(0.75 * sqrt(5.0 / (2.0 * M_PI)));
            const float c_0  = (float)((3.0 / 16.0) * sqrt(1.0 / M_PI));
            const float c_p2 = (float)((3.0 / 8.0) * sqrt(5.0 / M_PI));
            const float c_p4 = (float)((3.0 / 16.0) * sqrt(35.0 / M_PI));
            s0[0] = (_Float16)(c_m4 * vx * vy * (x2 - y2));
            s0[1] = (_Float16)(c_m3 * vy * vz * (3.0f * x2 - y2));
            s0[2] = (_Float16)(c_m2 * vx * vy * (7.0f * z2 - 1.0f));
            s0[3] = (_Float16)(c_m1 * vy * vz * (7.0f * z2 - 3.0f));
            s1[0] = (_Float16)(c_0  * (35.0f * z2 * z2 - 30.0f * z2 + 3.0f));
            s1[1] = (_Float16)(c_m1 * vx * vz * (7.0f * z2 - 3.0f));
            s1[2] = (_Float16)(c_p2 * (x2 - y2) * (7.0f * z2 - 1.0f));
            s1[3] = (_Float16)(c_m3 * vx * vz * (x2 - y2));
            s2[0] = (_Float16)(c_p4 * (x2 * x2 - 6.0f * x2 * y2 + y2 * y2));  // k=8
            s2[1] = (_Float16)x;   // k=9..11: raw grid vec (pass2 dot)
            s2[2] = (_Float16)y;
            s2[3] = (_Float16)z;
            s3 = (half4){0, 0, 0, 0};      // k=12..15 = 0
        }
        half4* row = lds4 + lr * 5;        // 5 half4 = 20 halfs = 40 B pitch (bank-friendly)
        row[0] = s0; row[1] = s1; row[2] = s2; row[3] = s3;
    }
}

// B-operand frag (f4 for one b column): B[k][col]: col=lane&31, k=(lane>>5)*8+j.
__device__ inline half8 make_bfrag(const float* __restrict__ f4, int b, int kh) {
    half8 a = {0, 0, 0, 0, 0, 0, 0, 0};
    const float* fr = f4 + (size_t)b * 9;
    if (kh == 0) {
#pragma unroll
        for (int j = 0; j < 8; ++j) a[j] = (_Float16)fr[j];
    } else {
        a[0] = (_Float16)fr[8];      // k=8
    }
    return a;
}

// merge (v2,g2) into (v,g) with numpy first-max semantics
__device__ inline void merge_vg(float& v, int& g, float v2, int g2) {
    bool take = (v2 > v) || (v2 == v && g2 < g);
    v = take ? v2 : v;
    g = take ? g2 : g;
}

// ---------------- Kernel 1: pass-1 argmax, packed tree-reduce ----------------
__global__ __launch_bounds__(256, 6) void k_pass1(const float* __restrict__ f4,
                                                  const float* __restrict__ gv,
                                                  float* __restrict__ Pv,
                                                  int* __restrict__ Pi) {
    __shared__ half4 lds4[MAXTPC * 32 * 5];    // 20480 B -> 8 blocks/CU
    const int lane = threadIdx.x & 63;
    const int w = threadIdx.x >> 6;
    const int W = blockIdx.x * 4 + w;          // b-tile; b = 32W .. 32W+31
    const int n = lane & 31, kh = lane >> 5;
    const int chunk = blockIdx.y;
    const int b = W * 32 + n;

    const int t0 = (NGT * chunk) / NCH;
    const int t1 = (NGT * (chunk + 1)) / NCH;
    const int nt = t1 - t0;

    stage_sh(gv, lds4, t0, nt);
    const half8 bf = make_bfrag(f4, b, kh);
    __syncthreads();

    const floatx16 zero16 = {0.f,0.f,0.f,0.f, 0.f,0.f,0.f,0.f, 0.f,0.f,0.f,0.f, 0.f,0.f,0.f,0.f};
    const unsigned mskc = 0xFFFFFFF0u;
    float run = -INFINITY; int bt = 0;

    const half4* lp = lds4 + n * 5 + kh * 2;   // 8 halfs at k-offset kh*8
    half4 a0 = lp[0], a1 = lp[1]; lp += 32 * 5;

    for (int t = 0; t < nt - 1; ++t) {
        half4 b0 = lp[0], b1 = lp[1]; lp += 32 * 5;
        half8 af = __builtin_shufflevector(a0, a1, 0, 1, 2, 3, 4, 5, 6, 7);
        floatx16 c = __builtin_amdgcn_mfma_f32_32x32x16_f16(af, bf, zero16, 0, 0, 0);
        float p0,p1,p2,p3,p4,p5,p6,p7,p8,p9,p10,p11,p12,p13,p14,p15;
        PACKF(p0,  c[0],  "15"); PACKF(p1,  c[1],  "14");
        PACKF(p2,  c[2],  "13"); PACKF(p3,  c[3],  "12");
        PACKF(p4,  c[4],  "11"); PACKF(p5,  c[5],  "10");
        PACKF(p6,  c[6],  "9");  PACKF(p7,  c[7],  "8");
        PACKF(p8,  c[8],  "7");  PACKF(p9,  c[9],  "6");
        PACKF(p10, c[10], "5");  PACKF(p11, c[11], "4");
        PACKF(p12, c[12], "3");  PACKF(p13, c[13], "2");
        PACKF(p14, c[14], "1");  PACKF(p15, c[15], "0");
        float u0 = max3f(p0, p1, p2);
        float u1 = max3f(p3, p4, p5);
        float u2 = max3f(p6, p7, p8);
        float u3 = max3f(p9, p10, p11);
        float u4 = max3f(p12, p13, p14);
        float u5 = max3f(u0, u1, p15);
        float u6 = max3f(u2, u3, u4);
        float tm = fmaxf(u5, u6);
        bt = (tm > run) ? t : bt;
        run = fmaxf(run, tm);
        a0 = b0; a1 = b1;
    }
    {   // peeled last tile; tail-NaN scrub only where the tail lives (last chunk)
        half8 af = __builtin_shufflevector(a0, a1, 0, 1, 2, 3, 4, 5, 6, 7);
        floatx16 c = __builtin_amdgcn_mfma_f32_32x32x16_f16(af, bf, zero16, 0, 0, 0);
        if (chunk == NCH - 1) {
#pragma unroll
            for (int r = 0; r < 16; ++r) c[r] = fmaxf(c[r], -3.0e38f);
        }
        float p0,p1,p2,p3,p4,p5,p6,p7,p8,p9,p10,p11,p12,p13,p14,p15;
        PACKF(p0,  c[0],  "15"); PACKF(p1,  c[1],  "14");
        PACKF(p2,  c[2],  "13"); PACKF(p3,  c[3],  "12");
        PACKF(p4,  c[4],  "11"); PACKF(p5,  c[5],  "10");
        PACKF(p6,  c[6],  "9");  PACKF(p7,  c[7],  "8");
        PACKF(p8,  c[8],  "7");  PACKF(p9,  c[9],  "6");
        PACKF(p10, c[10], "5");  PACKF(p11, c[11], "4");
        PACKF(p12, c[12], "3");  PACKF(p13, c[13], "2");
        PACKF(p14, c[14], "1");  PACKF(p15, c[15], "0");
        float u0 = max3f(p0, p1, p2);
        float u1 = max3f(p3, p4, p5);
        float u2 = max3f(p6, p7, p8);
        float u3 = max3f(p9, p10, p11);
        float u4 = max3f(p12, p13, p14);
        float u5 = max3f(u0, u1, p15);
        float u6 = max3f(u2, u3, u4);
        float tm = fmaxf(u5, u6);
        bt = (tm > run) ? (nt - 1) : bt;
        run = fmaxf(run, tm);
    }
    // unpack: field = 15 - r  ->  r = 15 - (bits & 15); row = ROWMAP(r, kh)
    unsigned rb = __float_as_uint(run);
    int rwin = 15 - (int)(rb & 15u);
    int row = ROWMAP(rwin, kh);
    float v = __uint_as_float(rb & 0xFFFFFFF0u);
    int g = (t0 + bt) * 32 + row;
    merge_vg(v, g, __shfl_xor(v, 32), __shfl_xor(g, 32));
    if (kh == 0) {
        Pv[(size_t)chunk * NB + b] = v;
        Pi[(size_t)chunk * NB + b] = g;
    }
}

// ---------------- Kernel 1.5: reduce P1 across chunks -> z-axis per b ----------------
__global__ __launch_bounds__(256) void k_zred(const float* __restrict__ P1v,
                                              const int* __restrict__ P1i,
                                              const float* __restrict__ gv,
                                              float* __restrict__ zax) {
    const int b = blockIdx.x * 256 + threadIdx.x;
    float bz = -INFINITY; int zi = 0;
#pragma unroll
    for (int cc = 0; cc < NCH; ++cc) {
        float v = P1v[(size_t)cc * NB + b];
        int   i = P1i[(size_t)cc * NB + b];
        if (v > bz || (v == bz && i < zi)) { bz = v; zi = i; }
    }
    float4 z4 = {gv[3 * zi + 0], gv[3 * zi + 1], gv[3 * zi + 2], 0.f};
    *(float4*)(zax + 4 * (size_t)b) = z4;
}

// ---------------- Kernel 2: pass-2 masked argmax, dual MFMA, packed tree ----------------
__global__ __launch_bounds__(256, 6) void k_pass2(const float* __restrict__ f4,
                                                  const float* __restrict__ gv,
                                                  const float* __restrict__ zax,
                                                  float* __restrict__ P2v,
                                                  int* __restrict__ P2i) {
    __shared__ half4 lds4[MAXTPC * 32 * 5];
    const int lane = threadIdx.x & 63;
    const int w = threadIdx.x >> 6;
    const int W = blockIdx.x * 4 + w;
    const int n = lane & 31, kh = lane >> 5;
    const int chunk = blockIdx.y;
    const int b = W * 32 + n;

    const int t0 = (NGT * chunk) / NCH;
    const int t1 = (NGT * (chunk + 1)) / NCH;
    const int nt = t1 - t0;

    stage_sh(gv, lds4, t0, nt);
    const half8 bf = make_bfrag(f4, b, kh);
    half8 df = {0, 0, 0, 0, 0, 0, 0, 0};
    if (kh == 1) {                           // z_b at k=9,10,11 -> j=1..3
        const float* zp = zax + 4 * (size_t)b;
        df[1] = (_Float16)zp[0];
        df[2] = (_Float16)zp[1];
        df[3] = (_Float16)zp[2];
    }
    __syncthreads();

    const floatx16 zero16 = {0.f,0.f,0.f,0.f, 0.f,0.f,0.f,0.f, 0.f,0.f,0.f,0.f, 0.f,0.f,0.f,0.f};
    const unsigned mskc = 0xFFFFFFF0u;
    const float ninf = -INFINITY;
    const float lim = 0.2f;
    float run = -INFINITY; int bt = 0;

    const half4* lp = lds4 + n * 5 + kh * 2;
    half4 a0 = lp[0], a1 = lp[1]; lp += 32 * 5;

    for (int t = 0; t < nt; ++t) {
        half4 b0, b1;
        if (t < nt - 1) { b0 = lp[0]; b1 = lp[1]; lp += 32 * 5; }
        half8 af = __builtin_shufflevector(a0, a1, 0, 1, 2, 3, 4, 5, 6, 7);
        floatx16 cs = __builtin_amdgcn_mfma_f32_32x32x16_f16(af, bf, zero16, 0, 0, 0);
        floatx16 cd = __builtin_amdgcn_mfma_f32_32x32x16_f16(af, df, zero16, 0, 0, 0);
        // per reg: pack row-field into cs, then mask by |dot|<0.2 (NaN dot -> -inf, kills tail)
        float q;
        float s0,s1,s2,s3,s4,s5,s6,s7,s8,s9,s10,s11,s12,s13,s14,s15;
        PACKF(q, cs[0],  "15"); s0  = (fabsf(cd[0])  < lim) ? q : ninf;
        PACKF(q, cs[1],  "14"); s1  = (fabsf(cd[1])  < lim) ? q : ninf;
        PACKF(q, cs[2],  "13"); s2  = (fabsf(cd[2])  < lim) ? q : ninf;
        PACKF(q, cs[3],  "12"); s3  = (fabsf(cd[3])  < lim) ? q : ninf;
        PACKF(q, cs[4],  "11"); s4  = (fabsf(cd[4])  < lim) ? q : ninf;
        PACKF(q, cs[5],  "10"); s5  = (fabsf(cd[5])  < lim) ? q : ninf;
        PACKF(q, cs[6],  "9");  s6  = (fabsf(cd[6])  < lim) ? q : ninf;
        PACKF(q, cs[7],  "8");  s7  = (fabsf(cd[7])  < lim) ? q : ninf;
        PACKF(q, cs[8],  "7");  s8  = (fabsf(cd[8])  < lim) ? q : ninf;
        PACKF(q, cs[9],  "6");  s9  = (fabsf(cd[9])  < lim) ? q : ninf;
        PACKF(q, cs[10], "5");  s10 = (fabsf(cd[10]) < lim) ? q : ninf;
        PACKF(q, cs[11], "4");  s11 = (fabsf(cd[11]) < lim) ? q : ninf;
        PACKF(q, cs[12], "3");  s12 = (fabsf(cd[12]) < lim) ? q : ninf;
        PACKF(q, cs[13], "2");  s13 = (fabsf(cd[13]) < lim) ? q : ninf;
        PACKF(q, cs[14], "1");  s14 = (fabsf(cd[14]) < lim) ? q : ninf;
        PACKF(q, cs[15], "0");  s15 = (fabsf(cd[15]) < lim) ? q : ninf;
        float u0 = max3f(s0, s1, s2);
        float u1 = max3f(s3, s4, s5);
        float u2 = max3f(s6, s7, s8);
        float u3 = max3f(s9, s10, s11);
        float u4 = max3f(s12, s13, s14);
        float u5 = max3f(u0, u1, s15);
        float u6 = max3f(u2, u3, u4);
        float tm = fmaxf(u5, u6);
        bt = (tm > run) ? t : bt;
        run = fmaxf(run, tm);
        a0 = b0; a1 = b1;
    }
    unsigned rb = __float_as_uint(run);
    int rwin = 15 - (int)(rb & 15u);
    int row = ROWMAP(rwin, kh);
    float v = __uint_as_float(rb & 0xFFFFFFF0u);
    int g = (t0 + bt) * 32 + row;
    merge_vg(v, g, __shfl_xor(v, 32), __shfl_xor(g, 32));
    if (kh == 0) {
        P2v[(size_t)chunk * NB + b] = v;
        P2i[(size_t)chunk * NB + b] = g;
    }
}

// ---------------- Kernel 3: finalize — frame, quaternion, boundary map ----------------
__global__ __launch_bounds__(256) void k_final(const float* __restrict__ f0,
                                               const float* __restrict__ gv,
                                               const float* __restrict__ zax,
                                               const float* __restrict__ P2v,
                                               const int* __restrict__ P2i,
                                               float* __restrict__ out) {
    int b = blockIdx.x * 256 + threadIdx.x;
    float bx = -INFINITY; int xi = 0;
#pragma unroll
    for (int cc = 0; cc < NCH; ++cc) {
        float v = P2v[(size_t)cc * NB + b];
        int   i = P2i[(size_t)cc * NB + b];
        if (v > bx || (v == bx && i < xi)) { bx = v; xi = i; }
    }
    const float* zp = zax + 4 * (size_t)b;
    float zr0 = zp[0], zr1 = zp[1], zr2 = zp[2];
    float xr0 = gv[3 * xi], xr1 = gv[3 * xi + 1], xr2 = gv[3 * xi + 2];
    float zn = sqrtf(zr0 * zr0 + zr1 * zr1 + zr2 * zr2);
    float zd = fmaxf(zn, 1e-12f);
    float z0 = zr0 / zd, z1 = zr1 / zd, z2 = zr2 / zd;
    float pr = xr0 * z0 + xr1 * z1 + xr2 * z2;
    float ux = xr0 - pr * z0, uy = xr1 - pr * z1, uz = xr2 - pr * z2;
    float xn = sqrtf(ux * ux + uy * uy + uz * uz);
    float xd = fmaxf(xn, 1e-12f);
    float x0 = ux / xd, x1 = uy / xd, x2 = uz / xd;
    float y0 = z1 * x2 - z2 * x1;
    float y1 = z2 * x0 - z0 * x2;
    float y2 = z0 * x1 - z1 * x0;
    float m00 = x0, m01 = y0, m02 = z0;
    float m10 = x1, m11 = y1, m12 = z1;
    float m20 = x2, m21 = y2, m22 = z2;
    float q0 = sqrtf(fmaxf(1.0f + m00 + m11 + m22, 0.0f));
    float q1 = sqrtf(fmaxf(1.0f + m00 - m11 - m22, 0.0f));
    float q2 = sqrtf(fmaxf(1.0f - m00 + m11 - m22, 0.0f));
    float q3 = sqrtf(fmaxf(1.0f - m00 - m11 + m22, 0.0f));
    int bq = 0; float qb = q0;
    if (q1 > qb) { qb = q1; bq = 1; }
    if (q2 > qb) { qb = q2; bq = 2; }
    if (q3 > qb) { qb = q3; bq = 3; }
    float dd = 2.0f * fmaxf(qb, 0.1f);
    float wq, qx, qy, qz;
    if (bq == 0)      { wq = q0 * q0;  qx = m21 - m12; qy = m02 - m20; qz = m10 - m01; }
    else if (bq == 1) { wq = m21 - m12; qx = q1 * q1;  qy = m10 + m01; qz = m02 + m20; }
    else if (bq == 2) { wq = m02 - m20; qx = m10 + m01; qy = q2 * q2;  qz = m12 + m21; }
    else              { wq = m10 - m01; qx = m20 + m02; qy = m21 + m12; qz = q3 * q3; }
    out[b * 4 + 0] = wq / dd;
    out[b * 4 + 1] = qx / dd;
    out[b * 4 + 2] = qy / dd;
    out[b * 4 + 3] = qz / dd;
    out[4 * NB + b] = f0[b] * (float)(180.0 / M_PI);
}

extern "C" void kernel_launch(void* const* d_in, const int* in_sizes, int n_in,
                              void* d_out, int out_size, void* d_ws, size_t ws_size,
                              hipStream_t stream) {
    const float* f0 = (const float*)d_in[0];   // [16384, 1]
    const float* f4 = (const float*)d_in[2];   // [16384, 9]
    const float* gv = (const float*)d_in[4];   // [10000, 3]
    float* out = (float*)d_out;
    (void)in_sizes; (void)n_in; (void)out_size; (void)ws_size;

    // ws layout (1.5 MB stride): P1v | P1i | P2v | P2i | zax  (NCH*NB*4 = 1.31 MB each)
    char* W = (char*)d_ws;
    float* P1v = (float*)(W + 0);
    int*   P1i = (int*)(W + 0x180000);
    float* P2v = (float*)(W + 2 * 0x180000);
    int*   P2i = (int*)(W + 3 * 0x180000);
    float* zax = (float*)(W + 4 * 0x180000);   // [NB][4] floats

    // 512 b-tiles / 4 waves = 128 blocks x; 20 chunks y = 2560 blocks, 8/CU resident
    dim3 grid2(128, NCH);
    k_pass1<<<grid2, 256, 0, stream>>>(f4, gv, P1v, P1i);
    k_zred<<<NB / 256, 256, 0, stream>>>(P1v, P1i, gv, zax);
    k_pass2<<<grid2, 256, 0, stream>>>(f4, gv, zax, P2v, P2i);
    k_final<<<NB / 256, 256, 0, stream>>>(f0, gv, zax, P2v, P2i, out);
}